// Round 1
// 356.614 us; speedup vs baseline: 1.1872x; 1.1872x over previous
//
#include <hip/hip_runtime.h>
#include <hip/hip_bf16.h>
#include <math.h>

// Problem constants (H=W=128 passed as inputs but fixed for this problem)
#define B_ 4
#define HH 128
#define WW 128
#define CC 256
#define LL (HH * WW)          // 16384
#define NROWS (B_ * LL)       // 65536
#define NREL 945              // (2*8-1)*(2*32-1)
#define SCALE 0.17677669529663687f  // 32^-0.5

typedef __attribute__((ext_vector_type(8))) _Float16 half8;
typedef __attribute__((ext_vector_type(4))) float f32x4;

// fp16 <-> fp32 (RTNE via v_cvt)
__device__ __forceinline__ unsigned short f2h(float f) {
    union { _Float16 h; unsigned short u; } v;
    v.h = (_Float16)f;
    return v.u;
}
__device__ __forceinline__ float h2f(unsigned short u) {
    union { unsigned short u; _Float16 h; } v;
    v.u = u;
    return (float)v.h;
}
// async global->LDS, 16 B per lane (dest = wave-uniform base + lane*16)
__device__ __forceinline__ void gl_lds16(const unsigned short* g, unsigned short* l) {
    __builtin_amdgcn_global_load_lds((const __attribute__((address_space(1))) void*)g,
                                     (__attribute__((address_space(3))) void*)l, 16, 0, 0);
}

// ---------------------------------------------------------------------------
// DynamicPosBias MLP (tiny) + bias-table expansion (unchanged, validated)
// ---------------------------------------------------------------------------
__device__ inline void ln_relu8(float* v, const float* g, const float* b) {
    float m = 0.f;
#pragma unroll
    for (int j = 0; j < 8; j++) m += v[j];
    m *= 0.125f;
    float var = 0.f;
#pragma unroll
    for (int j = 0; j < 8; j++) { float d = v[j] - m; var += d * d; }
    var *= 0.125f;
    float inv = 1.0f / sqrtf(var + 1e-5f);
#pragma unroll
    for (int j = 0; j < 8; j++) {
        float xn = (v[j] - m) * inv * g[j] + b[j];
        v[j] = xn > 0.f ? xn : 0.f;
    }
}

__device__ inline void mat8x8(const float* in, float* out, const float* w, const float* bias) {
#pragma unroll
    for (int j = 0; j < 8; j++) {
        float s = bias[j];
#pragma unroll
        for (int i = 0; i < 8; i++) s = fmaf(in[i], w[i * 8 + j], s);
        out[j] = s;
    }
}

__global__ void pos_kernel(const float* __restrict__ pp_w, const float* __restrict__ pp_b,
                           const float* __restrict__ ln1_g, const float* __restrict__ ln1_b,
                           const float* __restrict__ l1_w, const float* __restrict__ l1_b,
                           const float* __restrict__ ln2_g, const float* __restrict__ ln2_b,
                           const float* __restrict__ l2_w, const float* __restrict__ l2_b,
                           const float* __restrict__ ln3_g, const float* __restrict__ ln3_b,
                           const float* __restrict__ l3_w, const float* __restrict__ l3_b,
                           float* __restrict__ pos) {
    const int br = blockIdx.x;
    const int Wsp = br ? 8 : 32;
    const int Hsp = br ? 32 : 8;
    const int W2 = 2 * Wsp - 1;
    const int nrel = (2 * Hsp - 1) * W2;  // 945 both branches
    for (int r = threadIdx.x; r < nrel; r += blockDim.x) {
        float dy = (float)(r / W2 - (Hsp - 1));
        float dx = (float)(r % W2 - (Wsp - 1));
        float p[8], t[8];
#pragma unroll
        for (int j = 0; j < 8; j++)
            p[j] = dy * pp_w[br * 16 + j] + dx * pp_w[br * 16 + 8 + j] + pp_b[br * 8 + j];
        ln_relu8(p, ln1_g + br * 8, ln1_b + br * 8);
        mat8x8(p, t, l1_w + br * 64, l1_b + br * 8);
        ln_relu8(t, ln2_g + br * 8, ln2_b + br * 8);
        mat8x8(t, p, l2_w + br * 64, l2_b + br * 8);
        ln_relu8(p, ln3_g + br * 8, ln3_b + br * 8);
#pragma unroll
        for (int j = 0; j < 4; j++) {
            float s = l3_b[br * 4 + j];
#pragma unroll
            for (int i = 0; i < 8; i++) s = fmaf(p[i], l3_w[br * 32 + i * 4 + j], s);
            pos[(br * NREL + r) * 4 + j] = s;
        }
    }
}

// T2[br][h][n(query)][m(key)]
__global__ void rpb_kernel(const float* __restrict__ pos, float* __restrict__ T2) {
    const int m = threadIdx.x;       // key
    const int n = blockIdx.x;        // query
    const int h = blockIdx.y;
    const int br = blockIdx.z;
    const int logW = br ? 3 : 5;
    const int Wsp = 1 << logW;
    const int Hsp = 256 >> logW;
    const int W2 = 2 * Wsp - 1;
    const int i_n = n >> logW, j_n = n & (Wsp - 1);
    const int i_m = m >> logW, j_m = m & (Wsp - 1);
    const int idx = (i_n - i_m + Hsp - 1) * W2 + (j_n - j_m + Wsp - 1);
    T2[(((size_t)(br * 4 + h) * 256) + n) * 256 + m] = pos[(br * NREL + idx) * 4 + h];
}

// Transpose weights: w[K x N] fp32 -> th[N x K] fp16
__global__ void convw_kernel(const float* __restrict__ w, unsigned short* __restrict__ th,
                             int Kd, int Nd) {
    int idx = blockIdx.x * blockDim.x + threadIdx.x;  // n*K + k
    if (idx >= Kd * Nd) return;
    int n = idx / Kd, k = idx - n * Kd;
    th[idx] = f2h(w[(size_t)k * Nd + n]);
}

// x fp32 [M][256] -> xh fp16 (row-major)
__global__ __launch_bounds__(256) void convx_kernel(const float* __restrict__ x,
                                                    unsigned short* __restrict__ xh) {
    size_t i = ((size_t)blockIdx.x * 256 + threadIdx.x) * 4;
    float4 v = *(const float4*)(x + i);
    ushort4 h;
    h.x = f2h(v.x); h.y = f2h(v.y); h.z = f2h(v.z); h.w = f2h(v.w);
    *(ushort4*)(xh + i) = h;
}

// ---------------------------------------------------------------------------
// gemm_f16: C_f16[M][ldc] = A_f16 @ B_f16^T  (single-term, m97 structure).
// 128x128 tile, BK=32, 4 waves x 4x4 16x16 tiles. N-block fastest for A reuse,
// bijective XCD swizzle (grid % 8 == 0) for L2 locality of the A panel.
// ---------------------------------------------------------------------------
__global__ __launch_bounds__(256) void gemm_f16(const unsigned short* __restrict__ A,
                                                const unsigned short* __restrict__ B,
                                                unsigned short* __restrict__ C,
                                                int ldc, int nblk) {
    const int K = 256;
    __shared__ unsigned short sA[4096];  // [128][32]
    __shared__ unsigned short sB[4096];

    const int tid = threadIdx.x;
    // XCD-aware bijective swizzle: grid (3072) % 8 == 0
    const int cpx = gridDim.x >> 3;
    const int bid = blockIdx.x;
    const int swz = (bid & 7) * cpx + (bid >> 3);
    const int nb = swz % nblk;                 // N fastest: A-tile L2 reuse
    const int mb = swz / nblk;
    const size_t blockM = (size_t)mb * 128;
    const int blockN = nb * 128;

    const int srow = tid >> 2;                 // staging row 0..63
    const int schunk = (tid & 3) * 8;          // k-chunk
    const unsigned short* pA = A + (blockM + srow) * K + schunk;
    const unsigned short* pB = B + (size_t)(blockN + srow) * K + schunk;
    const size_t rstep = (size_t)64 * K;

    const int w = tid >> 6;
    const int lane = tid & 63;
    const int quad = lane >> 4;
    const int l15 = lane & 15;
    const int wm = (w & 1) * 64;
    const int wn = (w >> 1) * 64;

    f32x4 acc[4][4];
#pragma unroll
    for (int i = 0; i < 4; i++)
#pragma unroll
        for (int j = 0; j < 4; j++) acc[i][j] = (f32x4){0.f, 0.f, 0.f, 0.f};

    for (int kb = 0; kb < K; kb += 32) {
        gl_lds16(pA + kb, sA + tid * 8);
        gl_lds16(pA + kb + rstep, sA + 2048 + tid * 8);
        gl_lds16(pB + kb, sB + tid * 8);
        gl_lds16(pB + kb + rstep, sB + 2048 + tid * 8);
        __syncthreads();

        half8 fa[4], fb[4];
#pragma unroll
        for (int i = 0; i < 4; i++) {
            fa[i] = *(const half8*)(sA + (wm + i * 16 + l15) * 32 + quad * 8);
            fb[i] = *(const half8*)(sB + (wn + i * 16 + l15) * 32 + quad * 8);
        }
#pragma unroll
        for (int i = 0; i < 4; i++)
#pragma unroll
            for (int j = 0; j < 4; j++)
                acc[i][j] = __builtin_amdgcn_mfma_f32_16x16x32_f16(fa[i], fb[j], acc[i][j], 0, 0, 0);
        __syncthreads();
    }

#pragma unroll
    for (int j = 0; j < 4; j++) {
        int col = blockN + wn + j * 16 + l15;
#pragma unroll
        for (int i = 0; i < 4; i++)
#pragma unroll
            for (int r = 0; r < 4; r++) {
                size_t row = blockM + wm + i * 16 + quad * 4 + r;
                C[row * ldc + col] = f2h(acc[i][j][r]);
            }
    }
}

// ---------------------------------------------------------------------------
// gemm_proj: C_f32[M][256] = A_f16 @ B_f16^T + bias  (single-term).
// ---------------------------------------------------------------------------
__global__ __launch_bounds__(256) void gemm_proj(const unsigned short* __restrict__ A,
                                                 const unsigned short* __restrict__ B,
                                                 float* __restrict__ C,
                                                 const float* __restrict__ bias) {
    const int K = 256;
    __shared__ unsigned short sA[4096];
    __shared__ unsigned short sB[4096];

    const int tid = threadIdx.x;
    const int cpx = gridDim.x >> 3;
    const int bid = blockIdx.x;
    const int swz = (bid & 7) * cpx + (bid >> 3);
    const int nb = swz & 1;
    const int mb = swz >> 1;
    const size_t blockM = (size_t)mb * 128;
    const int blockN = nb * 128;

    const int srow = tid >> 2;
    const int schunk = (tid & 3) * 8;
    const unsigned short* pA = A + (blockM + srow) * K + schunk;
    const unsigned short* pB = B + (size_t)(blockN + srow) * K + schunk;
    const size_t rstep = (size_t)64 * K;

    const int w = tid >> 6;
    const int lane = tid & 63;
    const int quad = lane >> 4;
    const int l15 = lane & 15;
    const int wm = (w & 1) * 64;
    const int wn = (w >> 1) * 64;

    f32x4 acc[4][4];
#pragma unroll
    for (int i = 0; i < 4; i++)
#pragma unroll
        for (int j = 0; j < 4; j++) acc[i][j] = (f32x4){0.f, 0.f, 0.f, 0.f};

    for (int kb = 0; kb < K; kb += 32) {
        gl_lds16(pA + kb, sA + tid * 8);
        gl_lds16(pA + kb + rstep, sA + 2048 + tid * 8);
        gl_lds16(pB + kb, sB + tid * 8);
        gl_lds16(pB + kb + rstep, sB + 2048 + tid * 8);
        __syncthreads();

        half8 fa[4], fb[4];
#pragma unroll
        for (int i = 0; i < 4; i++) {
            fa[i] = *(const half8*)(sA + (wm + i * 16 + l15) * 32 + quad * 8);
            fb[i] = *(const half8*)(sB + (wn + i * 16 + l15) * 32 + quad * 8);
        }
#pragma unroll
        for (int i = 0; i < 4; i++)
#pragma unroll
            for (int j = 0; j < 4; j++)
                acc[i][j] = __builtin_amdgcn_mfma_f32_16x16x32_f16(fa[i], fb[j], acc[i][j], 0, 0, 0);
        __syncthreads();
    }

#pragma unroll
    for (int j = 0; j < 4; j++) {
        int col = blockN + wn + j * 16 + l15;
        float bv = bias[col];
#pragma unroll
        for (int i = 0; i < 4; i++)
#pragma unroll
            for (int r = 0; r < 4; r++) {
                size_t row = blockM + wm + i * 16 + quad * 4 + r;
                C[row * 256 + col] = acc[i][j][r] + bv;
            }
    }
}

// ---------------------------------------------------------------------------
// MFMA window attention, fp16 qkv in / fp16 attb out (structure validated).
// SCALE applied to scores post-MFMA (exact).
// ---------------------------------------------------------------------------
__global__ __launch_bounds__(256) void attn_mfma(const unsigned short* __restrict__ qkvb,
                                                 const float* __restrict__ T2,
                                                 unsigned short* __restrict__ attb) {
    __shared__ unsigned short Ks[256][40];    // [key][d]
    __shared__ unsigned short Vt[32][264];    // [d][key]
    __shared__ unsigned short Pc[4][16][40];  // per-wave P chunk

    const int tid = threadIdx.x;
    const int wi = blockIdx.x;   // b*64 + window
    const int h = blockIdx.y;    // 0..3
    const int br = blockIdx.z;   // 0..1
    const int logW = br ? 3 : 5;
    const int Wsp = 1 << logW;
    const int Hsp = 256 >> logW;
    const int logNWx = br ? 4 : 2;
    const int b = wi >> 6;
    const int win = wi & 63;
    const int wy = win >> logNWx;
    const int wx = win & ((1 << logNWx) - 1);
    const int ccol = br * 128 + h * 32;

#pragma unroll
    for (int it = 0; it < 8; ++it) {
        int n = it * 32 + (tid >> 3);
        int d4 = (tid & 7) * 4;
        int iy = n >> logW, ix = n & (Wsp - 1);
        size_t row = ((size_t)b * LL + (wy * Hsp + iy) * WW + wx * Wsp + ix) * 768;
        ushort4 kv = *(const ushort4*)(qkvb + row + 256 + ccol + d4);
        ushort4 vv = *(const ushort4*)(qkvb + row + 512 + ccol + d4);
        *(ushort4*)&Ks[n][d4] = kv;
        Vt[d4 + 0][n] = vv.x;
        Vt[d4 + 1][n] = vv.y;
        Vt[d4 + 2][n] = vv.z;
        Vt[d4 + 3][n] = vv.w;
    }
    __syncthreads();

    const int w = tid >> 6;
    const int lane = tid & 63;
    const int quad = lane >> 4;
    const int l15 = lane & 15;
    const f32x4 zero = {0.f, 0.f, 0.f, 0.f};

#pragma unroll 1
    for (int qt = 0; qt < 4; ++qt) {
        const int qbase = qt * 64 + w * 16;
        const int qrow = qbase + l15;
        const int iyq = qrow >> logW, ixq = qrow & (Wsp - 1);
        const size_t qpix = (size_t)b * LL + (wy * Hsp + iyq) * WW + wx * Wsp + ixq;
        half8 qfrag = *(const half8*)(qkvb + qpix * 768 + ccol + quad * 8);

        const float* Tb = T2 + (((size_t)(br * 4 + h) * 256) + (qbase + quad * 4)) * 256 + l15;

        f32x4 o0 = zero, o1 = zero;
        float rsum[4] = {0.f, 0.f, 0.f, 0.f};

#pragma unroll 2
        for (int kc = 0; kc < 8; ++kc) {
            const int kb0 = kc * 32;
            half8 kf0 = *(const half8*)&Ks[kb0 + l15][quad * 8];
            half8 kf1 = *(const half8*)&Ks[kb0 + 16 + l15][quad * 8];
            f32x4 s0 = __builtin_amdgcn_mfma_f32_16x16x32_f16(qfrag, kf0, zero, 0, 0, 0);
            f32x4 s1 = __builtin_amdgcn_mfma_f32_16x16x32_f16(qfrag, kf1, zero, 0, 0, 0);
#pragma unroll
            for (int i = 0; i < 4; ++i) {
                float p0 = __expf(fmaf(s0[i], SCALE, Tb[(size_t)i * 256 + kb0]));
                float p1 = __expf(fmaf(s1[i], SCALE, Tb[(size_t)i * 256 + kb0 + 16]));
                rsum[i] += p0 + p1;
                Pc[w][quad * 4 + i][l15] = f2h(p0);
                Pc[w][quad * 4 + i][16 + l15] = f2h(p1);
            }
            half8 pf = *(const half8*)&Pc[w][l15][quad * 8];
            half8 vf0 = *(const half8*)&Vt[l15][kb0 + quad * 8];
            half8 vf1 = *(const half8*)&Vt[16 + l15][kb0 + quad * 8];
            o0 = __builtin_amdgcn_mfma_f32_16x16x32_f16(pf, vf0, o0, 0, 0, 0);
            o1 = __builtin_amdgcn_mfma_f32_16x16x32_f16(pf, vf1, o1, 0, 0, 0);
        }

#pragma unroll
        for (int i = 0; i < 4; ++i) {
            float s = rsum[i];
            s += __shfl_xor(s, 1, 64);
            s += __shfl_xor(s, 2, 64);
            s += __shfl_xor(s, 4, 64);
            s += __shfl_xor(s, 8, 64);
            rsum[i] = 1.0f / s;
        }

#pragma unroll
        for (int i = 0; i < 4; ++i) {
            int r = qbase + quad * 4 + i;
            int iyr = r >> logW, ixr = r & (Wsp - 1);
            size_t pix = (size_t)b * LL + (wy * Hsp + iyr) * WW + wx * Wsp + ixr;
            unsigned short* op = attb + pix * 256 + ccol;
            op[l15] = f2h(o0[i] * rsum[i]);
            op[16 + l15] = f2h(o1[i] * rsum[i]);
        }
    }
}

// ---------------------------------------------------------------------------
// LePE: depthwise 3x3 on fp16 V, += (with bias) into fp16 attb (RMW).
// ---------------------------------------------------------------------------
__global__ __launch_bounds__(256) void lepe_kernel(const unsigned short* __restrict__ qkvb,
                                                   const float* __restrict__ w_dw,
                                                   const float* __restrict__ b_dw,
                                                   unsigned short* __restrict__ attb) {
    const int tid = threadIdx.x;
    const int c4 = (tid & 63) * 4;
    const int pix = blockIdx.x * 4 + (tid >> 6);
    const int bb = pix >> 14;
    const int y = (pix >> 7) & 127;
    const int x = pix & 127;

    float wreg[36];
    const float* wp = w_dw + c4 * 9;
#pragma unroll
    for (int q = 0; q < 9; q++) {
        float4 t = *(const float4*)(wp + q * 4);
        wreg[q * 4 + 0] = t.x; wreg[q * 4 + 1] = t.y;
        wreg[q * 4 + 2] = t.z; wreg[q * 4 + 3] = t.w;
    }

    float4 bv = *(const float4*)(b_dw + c4);
    ushort4 av = *(const ushort4*)(attb + ((size_t)pix << 8) + c4);
    float4 acc;
    acc.x = h2f(av.x) + bv.x; acc.y = h2f(av.y) + bv.y;
    acc.z = h2f(av.z) + bv.z; acc.w = h2f(av.w) + bv.w;

#pragma unroll
    for (int ky = 0; ky < 3; ky++) {
        int yy = y + ky - 1;
        if (yy < 0 || yy > 127) continue;
#pragma unroll
        for (int kx = 0; kx < 3; kx++) {
            int xx = x + kx - 1;
            if (xx < 0 || xx > 127) continue;
            int j = ky * 3 + kx;
            ushort4 v = *(const ushort4*)(qkvb + (((size_t)bb << 14) + yy * 128 + xx) * 768 + 512 + c4);
            acc.x = fmaf(h2f(v.x), wreg[0 * 9 + j], acc.x);
            acc.y = fmaf(h2f(v.y), wreg[1 * 9 + j], acc.y);
            acc.z = fmaf(h2f(v.z), wreg[2 * 9 + j], acc.z);
            acc.w = fmaf(h2f(v.w), wreg[3 * 9 + j], acc.w);
        }
    }
    ushort4 r;
    r.x = f2h(acc.x); r.y = f2h(acc.y); r.z = f2h(acc.z); r.w = f2h(acc.w);
    *(ushort4*)(attb + ((size_t)pix << 8) + c4) = r;
}

// ---------------------------------------------------------------------------
extern "C" void kernel_launch(void* const* d_in, const int* in_sizes, int n_in,
                              void* d_out, int out_size, void* d_ws, size_t ws_size,
                              hipStream_t stream) {
    const float* x     = (const float*)d_in[0];
    const float* w_qkv = (const float*)d_in[1];
    const float* w_proj= (const float*)d_in[2];
    const float* b_proj= (const float*)d_in[3];
    const float* w_dw  = (const float*)d_in[4];
    const float* b_dw  = (const float*)d_in[5];
    const float* pp_w  = (const float*)d_in[6];
    const float* pp_b  = (const float*)d_in[7];
    const float* ln1_g = (const float*)d_in[8];
    const float* ln1_b = (const float*)d_in[9];
    const float* l1_w  = (const float*)d_in[10];
    const float* l1_b  = (const float*)d_in[11];
    const float* ln2_g = (const float*)d_in[12];
    const float* ln2_b = (const float*)d_in[13];
    const float* l2_w  = (const float*)d_in[14];
    const float* l2_b  = (const float*)d_in[15];
    const float* ln3_g = (const float*)d_in[16];
    const float* ln3_b = (const float*)d_in[17];
    const float* l3_w  = (const float*)d_in[18];
    const float* l3_b  = (const float*)d_in[19];

    // Workspace layout (~162.5 MiB, fits prior 195 MiB footprint):
    float* pos = (float*)d_ws;                               // 7,680 f
    float* T2  = pos + 7680;                                 // 524,288 f
    unsigned short* qkvb = (unsigned short*)(T2 + 524288);   // 65536*768 sh (96 MiB, fp16)
    unsigned short* attb = qkvb + (size_t)NROWS * 768;       // 65536*256 sh (32 MiB, fp16)
    unsigned short* xh   = attb + (size_t)NROWS * 256;       // 32 MiB fp16
    unsigned short* wqh  = xh + (size_t)NROWS * 256;         // 196,608 sh
    unsigned short* wph  = wqh + 768 * 256;                  // 65,536 sh

    pos_kernel<<<2, 128, 0, stream>>>(pp_w, pp_b, ln1_g, ln1_b, l1_w, l1_b,
                                      ln2_g, ln2_b, l2_w, l2_b, ln3_g, ln3_b,
                                      l3_w, l3_b, pos);
    rpb_kernel<<<dim3(256, 4, 2), 256, 0, stream>>>(pos, T2);
    convw_kernel<<<768, 256, 0, stream>>>(w_qkv, wqh, 256, 768);
    convw_kernel<<<256, 256, 0, stream>>>(w_proj, wph, 256, 256);
    convx_kernel<<<NROWS / 4, 256, 0, stream>>>(x, xh);
    // qkv_f16 = x @ w_qkv   (single-term fp16, global_load_lds staging, XCD swizzle)
    gemm_f16<<<(NROWS / 128) * 6, 256, 0, stream>>>(xh, wqh, qkvb, 768, 6);
    // window attention -> attb (fp16)
    attn_mfma<<<dim3(256, 4, 2), 256, 0, stream>>>(qkvb, T2, attb);
    // LePE += depthwise conv on V (fp16 RMW)
    lepe_kernel<<<(B_ * LL) / 4, 256, 0, stream>>>(qkvb, w_dw, b_dw, attb);
    // d_out = attb @ w_proj + b_proj  (single-term fp16, fp32 out, direct to d_out)
    gemm_proj<<<(NROWS / 128) * 2, 256, 0, stream>>>(attb, wph, (float*)d_out, b_proj);
}

// Round 3
// 349.541 us; speedup vs baseline: 1.2112x; 1.0202x over previous
//
#include <hip/hip_runtime.h>
#include <hip/hip_bf16.h>
#include <math.h>

// Problem constants (H=W=128 passed as inputs but fixed for this problem)
#define B_ 4
#define HH 128
#define WW 128
#define CC 256
#define LL (HH * WW)          // 16384
#define NROWS (B_ * LL)       // 65536
#define NREL 945              // (2*8-1)*(2*32-1)
#define SCALE 0.17677669529663687f  // 32^-0.5
#define LOG2E 1.4426950408889634f
#define SCALE2 (0.17677669529663687f * 1.4426950408889634f)  // SCALE * log2(e)

typedef __attribute__((ext_vector_type(8))) _Float16 half8;
typedef __attribute__((ext_vector_type(2))) __fp16 fp16x2;
typedef __attribute__((ext_vector_type(4))) float f32x4;

// fp16 <-> fp32 (RTNE via v_cvt)
__device__ __forceinline__ unsigned short f2h(float f) {
    union { _Float16 h; unsigned short u; } v;
    v.h = (_Float16)f;
    return v.u;
}
__device__ __forceinline__ float h2f(unsigned short u) {
    union { unsigned short u; _Float16 h; } v;
    v.u = u;
    return (float)v.h;
}
// raw v_exp_f32: computes 2^x (hazard-interlocked VALU, safe as plain asm)
__device__ __forceinline__ float exp2_raw(float x) {
    float r;
    asm("v_exp_f32 %0, %1" : "=v"(r) : "v"(x));
    return r;
}
// async global->LDS, 16 B per lane (dest = wave-uniform base + lane*16)
__device__ __forceinline__ void gl_lds16(const unsigned short* g, unsigned short* l) {
    __builtin_amdgcn_global_load_lds((const __attribute__((address_space(1))) void*)g,
                                     (__attribute__((address_space(3))) void*)l, 16, 0, 0);
}

// ---------------------------------------------------------------------------
// DynamicPosBias MLP (tiny) + bias-table expansion (unchanged, validated)
// ---------------------------------------------------------------------------
__device__ inline void ln_relu8(float* v, const float* g, const float* b) {
    float m = 0.f;
#pragma unroll
    for (int j = 0; j < 8; j++) m += v[j];
    m *= 0.125f;
    float var = 0.f;
#pragma unroll
    for (int j = 0; j < 8; j++) { float d = v[j] - m; var += d * d; }
    var *= 0.125f;
    float inv = 1.0f / sqrtf(var + 1e-5f);
#pragma unroll
    for (int j = 0; j < 8; j++) {
        float xn = (v[j] - m) * inv * g[j] + b[j];
        v[j] = xn > 0.f ? xn : 0.f;
    }
}

__device__ inline void mat8x8(const float* in, float* out, const float* w, const float* bias) {
#pragma unroll
    for (int j = 0; j < 8; j++) {
        float s = bias[j];
#pragma unroll
        for (int i = 0; i < 8; i++) s = fmaf(in[i], w[i * 8 + j], s);
        out[j] = s;
    }
}

__global__ void pos_kernel(const float* __restrict__ pp_w, const float* __restrict__ pp_b,
                           const float* __restrict__ ln1_g, const float* __restrict__ ln1_b,
                           const float* __restrict__ l1_w, const float* __restrict__ l1_b,
                           const float* __restrict__ ln2_g, const float* __restrict__ ln2_b,
                           const float* __restrict__ l2_w, const float* __restrict__ l2_b,
                           const float* __restrict__ ln3_g, const float* __restrict__ ln3_b,
                           const float* __restrict__ l3_w, const float* __restrict__ l3_b,
                           float* __restrict__ pos) {
    const int br = blockIdx.x;
    const int Wsp = br ? 8 : 32;
    const int Hsp = br ? 32 : 8;
    const int W2 = 2 * Wsp - 1;
    const int nrel = (2 * Hsp - 1) * W2;  // 945 both branches
    for (int r = threadIdx.x; r < nrel; r += blockDim.x) {
        float dy = (float)(r / W2 - (Hsp - 1));
        float dx = (float)(r % W2 - (Wsp - 1));
        float p[8], t[8];
#pragma unroll
        for (int j = 0; j < 8; j++)
            p[j] = dy * pp_w[br * 16 + j] + dx * pp_w[br * 16 + 8 + j] + pp_b[br * 8 + j];
        ln_relu8(p, ln1_g + br * 8, ln1_b + br * 8);
        mat8x8(p, t, l1_w + br * 64, l1_b + br * 8);
        ln_relu8(t, ln2_g + br * 8, ln2_b + br * 8);
        mat8x8(t, p, l2_w + br * 64, l2_b + br * 8);
        ln_relu8(p, ln3_g + br * 8, ln3_b + br * 8);
#pragma unroll
        for (int j = 0; j < 4; j++) {
            float s = l3_b[br * 4 + j];
#pragma unroll
            for (int i = 0; i < 8; i++) s = fmaf(p[i], l3_w[br * 32 + i * 4 + j], s);
            pos[(br * NREL + r) * 4 + j] = s;
        }
    }
}

// T2[br][h][n(query)][m(key)], pre-scaled by log2(e) for the exp2 softmax path
__global__ void rpb_kernel(const float* __restrict__ pos, float* __restrict__ T2) {
    const int m = threadIdx.x;       // key
    const int n = blockIdx.x;        // query
    const int h = blockIdx.y;
    const int br = blockIdx.z;
    const int logW = br ? 3 : 5;
    const int Wsp = 1 << logW;
    const int Hsp = 256 >> logW;
    const int W2 = 2 * Wsp - 1;
    const int i_n = n >> logW, j_n = n & (Wsp - 1);
    const int i_m = m >> logW, j_m = m & (Wsp - 1);
    const int idx = (i_n - i_m + Hsp - 1) * W2 + (j_n - j_m + Wsp - 1);
    T2[(((size_t)(br * 4 + h) * 256) + n) * 256 + m] = pos[(br * NREL + idx) * 4 + h] * LOG2E;
}

// Transpose weights: w[K x N] fp32 -> th[N x K] fp16
__global__ void convw_kernel(const float* __restrict__ w, unsigned short* __restrict__ th,
                             int Kd, int Nd) {
    int idx = blockIdx.x * blockDim.x + threadIdx.x;  // n*K + k
    if (idx >= Kd * Nd) return;
    int n = idx / Kd, k = idx - n * Kd;
    th[idx] = f2h(w[(size_t)k * Nd + n]);
}

// x fp32 [M][256] -> xh fp16 (row-major)
__global__ __launch_bounds__(256) void convx_kernel(const float* __restrict__ x,
                                                    unsigned short* __restrict__ xh) {
    size_t i = ((size_t)blockIdx.x * 256 + threadIdx.x) * 4;
    float4 v = *(const float4*)(x + i);
    ushort4 h;
    h.x = f2h(v.x); h.y = f2h(v.y); h.z = f2h(v.z); h.w = f2h(v.w);
    *(ushort4*)(xh + i) = h;
}

// ---------------------------------------------------------------------------
// gemm_f16: C_f16[M][ldc] = A_f16 @ B_f16^T  (single-term, m97 structure).
// 128x128 tile, BK=32, 4 waves x 4x4 16x16 tiles. N-block fastest for A reuse,
// bijective XCD swizzle (grid % 8 == 0) for L2 locality of the A panel.
// ---------------------------------------------------------------------------
__global__ __launch_bounds__(256) void gemm_f16(const unsigned short* __restrict__ A,
                                                const unsigned short* __restrict__ B,
                                                unsigned short* __restrict__ C,
                                                int ldc, int nblk) {
    const int K = 256;
    __shared__ unsigned short sA[4096];  // [128][32]
    __shared__ unsigned short sB[4096];

    const int tid = threadIdx.x;
    // XCD-aware bijective swizzle: grid (3072) % 8 == 0
    const int cpx = gridDim.x >> 3;
    const int bid = blockIdx.x;
    const int swz = (bid & 7) * cpx + (bid >> 3);
    const int nb = swz % nblk;                 // N fastest: A-tile L2 reuse
    const int mb = swz / nblk;
    const size_t blockM = (size_t)mb * 128;
    const int blockN = nb * 128;

    const int srow = tid >> 2;                 // staging row 0..63
    const int schunk = (tid & 3) * 8;          // k-chunk
    const unsigned short* pA = A + (blockM + srow) * K + schunk;
    const unsigned short* pB = B + (size_t)(blockN + srow) * K + schunk;
    const size_t rstep = (size_t)64 * K;

    const int w = tid >> 6;
    const int lane = tid & 63;
    const int quad = lane >> 4;
    const int l15 = lane & 15;
    const int wm = (w & 1) * 64;
    const int wn = (w >> 1) * 64;

    f32x4 acc[4][4];
#pragma unroll
    for (int i = 0; i < 4; i++)
#pragma unroll
        for (int j = 0; j < 4; j++) acc[i][j] = (f32x4){0.f, 0.f, 0.f, 0.f};

    for (int kb = 0; kb < K; kb += 32) {
        gl_lds16(pA + kb, sA + tid * 8);
        gl_lds16(pA + kb + rstep, sA + 2048 + tid * 8);
        gl_lds16(pB + kb, sB + tid * 8);
        gl_lds16(pB + kb + rstep, sB + 2048 + tid * 8);
        __syncthreads();

        half8 fa[4], fb[4];
#pragma unroll
        for (int i = 0; i < 4; i++) {
            fa[i] = *(const half8*)(sA + (wm + i * 16 + l15) * 32 + quad * 8);
            fb[i] = *(const half8*)(sB + (wn + i * 16 + l15) * 32 + quad * 8);
        }
#pragma unroll
        for (int i = 0; i < 4; i++)
#pragma unroll
            for (int j = 0; j < 4; j++)
                acc[i][j] = __builtin_amdgcn_mfma_f32_16x16x32_f16(fa[i], fb[j], acc[i][j], 0, 0, 0);
        __syncthreads();
    }

#pragma unroll
    for (int j = 0; j < 4; j++) {
        int col = blockN + wn + j * 16 + l15;
#pragma unroll
        for (int i = 0; i < 4; i++)
#pragma unroll
            for (int r = 0; r < 4; r++) {
                size_t row = blockM + wm + i * 16 + quad * 4 + r;
                C[row * ldc + col] = f2h(acc[i][j][r]);
            }
    }
}

// ---------------------------------------------------------------------------
// gemm_proj: C_f32[M][256] = A_f16 @ B_f16^T + bias  (single-term).
// ---------------------------------------------------------------------------
__global__ __launch_bounds__(256) void gemm_proj(const unsigned short* __restrict__ A,
                                                 const unsigned short* __restrict__ B,
                                                 float* __restrict__ C,
                                                 const float* __restrict__ bias) {
    const int K = 256;
    __shared__ unsigned short sA[4096];
    __shared__ unsigned short sB[4096];

    const int tid = threadIdx.x;
    const int cpx = gridDim.x >> 3;
    const int bid = blockIdx.x;
    const int swz = (bid & 7) * cpx + (bid >> 3);
    const int nb = swz & 1;
    const int mb = swz >> 1;
    const size_t blockM = (size_t)mb * 128;
    const int blockN = nb * 128;

    const int srow = tid >> 2;
    const int schunk = (tid & 3) * 8;
    const unsigned short* pA = A + (blockM + srow) * K + schunk;
    const unsigned short* pB = B + (size_t)(blockN + srow) * K + schunk;
    const size_t rstep = (size_t)64 * K;

    const int w = tid >> 6;
    const int lane = tid & 63;
    const int quad = lane >> 4;
    const int l15 = lane & 15;
    const int wm = (w & 1) * 64;
    const int wn = (w >> 1) * 64;

    f32x4 acc[4][4];
#pragma unroll
    for (int i = 0; i < 4; i++)
#pragma unroll
        for (int j = 0; j < 4; j++) acc[i][j] = (f32x4){0.f, 0.f, 0.f, 0.f};

    for (int kb = 0; kb < K; kb += 32) {
        gl_lds16(pA + kb, sA + tid * 8);
        gl_lds16(pA + kb + rstep, sA + 2048 + tid * 8);
        gl_lds16(pB + kb, sB + tid * 8);
        gl_lds16(pB + kb + rstep, sB + 2048 + tid * 8);
        __syncthreads();

        half8 fa[4], fb[4];
#pragma unroll
        for (int i = 0; i < 4; i++) {
            fa[i] = *(const half8*)(sA + (wm + i * 16 + l15) * 32 + quad * 8);
            fb[i] = *(const half8*)(sB + (wn + i * 16 + l15) * 32 + quad * 8);
        }
#pragma unroll
        for (int i = 0; i < 4; i++)
#pragma unroll
            for (int j = 0; j < 4; j++)
                acc[i][j] = __builtin_amdgcn_mfma_f32_16x16x32_f16(fa[i], fb[j], acc[i][j], 0, 0, 0);
        __syncthreads();
    }

#pragma unroll
    for (int j = 0; j < 4; j++) {
        int col = blockN + wn + j * 16 + l15;
        float bv = bias[col];
#pragma unroll
        for (int i = 0; i < 4; i++)
#pragma unroll
            for (int r = 0; r < 4; r++) {
                size_t row = blockM + wm + i * 16 + quad * 4 + r;
                C[row * 256 + col] = acc[i][j][r] + bv;
            }
    }
}

// ---------------------------------------------------------------------------
// MFMA window attention, fp16 qkv in / fp16 attb out.
// Softmax via exp2 with pre-scaled T2 (SCALE2 = scale*log2e).
// P packed to LDS as u32 pairs (cvt_pkrtz); key dim permuted within each
// 32-chunk (slot = 2*(k&15) + (k>>4)) consistently in P and V layouts —
// legal since key is the reduction axis.
// LDS: Ks 16384 + Vt 16896 + Pc 5120 = 38400 B -> 4 blocks/CU.
// ---------------------------------------------------------------------------
__global__ __launch_bounds__(256) void attn_mfma(const unsigned short* __restrict__ qkvb,
                                                 const float* __restrict__ T2,
                                                 unsigned short* __restrict__ attb) {
    __shared__ unsigned short Ks[256][32];    // [key][d], no pad (reads stay balanced)
    __shared__ unsigned short Vt[32][264];    // [d][key-slot(permuted)]
    __shared__ unsigned int   Pc[4][16][20];  // per-wave packed P pairs [query][u32 slot]

    const int tid = threadIdx.x;
    const int wi = blockIdx.x;   // b*64 + window
    const int h = blockIdx.y;    // 0..3
    const int br = blockIdx.z;   // 0..1
    const int logW = br ? 3 : 5;
    const int Wsp = 1 << logW;
    const int Hsp = 256 >> logW;
    const int logNWx = br ? 4 : 2;
    const int b = wi >> 6;
    const int win = wi & 63;
    const int wy = win >> logNWx;
    const int wx = win & ((1 << logNWx) - 1);
    const int ccol = br * 128 + h * 32;

#pragma unroll
    for (int it = 0; it < 8; ++it) {
        int n = it * 32 + (tid >> 3);
        int d4 = (tid & 7) * 4;
        int iy = n >> logW, ix = n & (Wsp - 1);
        size_t row = ((size_t)b * LL + (wy * Hsp + iy) * WW + wx * Wsp + ix) * 768;
        ushort4 kv = *(const ushort4*)(qkvb + row + 256 + ccol + d4);
        ushort4 vv = *(const ushort4*)(qkvb + row + 512 + ccol + d4);
        *(ushort4*)&Ks[n][d4] = kv;
        // permuted key slot within each 32-key chunk: even slots = keys 0..15,
        // odd slots = keys 16..31 (matches packed P write order)
        int pos = (n & ~31) + 2 * (n & 15) + ((n >> 4) & 1);
        Vt[d4 + 0][pos] = vv.x;
        Vt[d4 + 1][pos] = vv.y;
        Vt[d4 + 2][pos] = vv.z;
        Vt[d4 + 3][pos] = vv.w;
    }
    __syncthreads();

    const int w = tid >> 6;
    const int lane = tid & 63;
    const int quad = lane >> 4;
    const int l15 = lane & 15;
    const f32x4 zero = {0.f, 0.f, 0.f, 0.f};

#pragma unroll 1
    for (int qt = 0; qt < 4; ++qt) {
        const int qbase = qt * 64 + w * 16;
        const int qrow = qbase + l15;
        const int iyq = qrow >> logW, ixq = qrow & (Wsp - 1);
        const size_t qpix = (size_t)b * LL + (wy * Hsp + iyq) * WW + wx * Wsp + ixq;
        half8 qfrag = *(const half8*)(qkvb + qpix * 768 + ccol + quad * 8);

        const float* Tb = T2 + (((size_t)(br * 4 + h) * 256) + (qbase + quad * 4)) * 256 + l15;

        f32x4 o0 = zero, o1 = zero;
        float rsum[4] = {0.f, 0.f, 0.f, 0.f};

#pragma unroll 2
        for (int kc = 0; kc < 8; ++kc) {
            const int kb0 = kc * 32;
            half8 kf0 = *(const half8*)&Ks[kb0 + l15][quad * 8];
            half8 kf1 = *(const half8*)&Ks[kb0 + 16 + l15][quad * 8];
            f32x4 s0 = __builtin_amdgcn_mfma_f32_16x16x32_f16(qfrag, kf0, zero, 0, 0, 0);
            f32x4 s1 = __builtin_amdgcn_mfma_f32_16x16x32_f16(qfrag, kf1, zero, 0, 0, 0);
#pragma unroll
            for (int i = 0; i < 4; ++i) {
                float e0 = exp2_raw(fmaf(s0[i], SCALE2, Tb[(size_t)i * 256 + kb0]));
                float e1 = exp2_raw(fmaf(s1[i], SCALE2, Tb[(size_t)i * 256 + kb0 + 16]));
                rsum[i] += e0 + e1;
                union { fp16x2 h; unsigned u; } cv;
                cv.h = __builtin_amdgcn_cvt_pkrtz(e0, e1);  // (key l15, key 16+l15)
                Pc[w][quad * 4 + i][l15] = cv.u;
            }
            half8 pf = *(const half8*)&Pc[w][l15][quad * 4];
            half8 vf0 = *(const half8*)&Vt[l15][kb0 + quad * 8];
            half8 vf1 = *(const half8*)&Vt[16 + l15][kb0 + quad * 8];
            o0 = __builtin_amdgcn_mfma_f32_16x16x32_f16(pf, vf0, o0, 0, 0, 0);
            o1 = __builtin_amdgcn_mfma_f32_16x16x32_f16(pf, vf1, o1, 0, 0, 0);
        }

#pragma unroll
        for (int i = 0; i < 4; ++i) {
            float s = rsum[i];
            s += __shfl_xor(s, 1, 64);
            s += __shfl_xor(s, 2, 64);
            s += __shfl_xor(s, 4, 64);
            s += __shfl_xor(s, 8, 64);
            rsum[i] = 1.0f / s;
        }

#pragma unroll
        for (int i = 0; i < 4; ++i) {
            int r = qbase + quad * 4 + i;
            int iyr = r >> logW, ixr = r & (Wsp - 1);
            size_t pix = (size_t)b * LL + (wy * Hsp + iyr) * WW + wx * Wsp + ixr;
            unsigned short* op = attb + pix * 256 + ccol;
            op[l15] = f2h(o0[i] * rsum[i]);
            op[16 + l15] = f2h(o1[i] * rsum[i]);
        }
    }
}

// ---------------------------------------------------------------------------
// LePE: depthwise 3x3 on fp16 V, += (with bias) into fp16 attb (RMW).
// ---------------------------------------------------------------------------
__global__ __launch_bounds__(256) void lepe_kernel(const unsigned short* __restrict__ qkvb,
                                                   const float* __restrict__ w_dw,
                                                   const float* __restrict__ b_dw,
                                                   unsigned short* __restrict__ attb) {
    const int tid = threadIdx.x;
    const int c4 = (tid & 63) * 4;
    const int pix = blockIdx.x * 4 + (tid >> 6);
    const int bb = pix >> 14;
    const int y = (pix >> 7) & 127;
    const int x = pix & 127;

    float wreg[36];
    const float* wp = w_dw + c4 * 9;
#pragma unroll
    for (int q = 0; q < 9; q++) {
        float4 t = *(const float4*)(wp + q * 4);
        wreg[q * 4 + 0] = t.x; wreg[q * 4 + 1] = t.y;
        wreg[q * 4 + 2] = t.z; wreg[q * 4 + 3] = t.w;
    }

    float4 bv = *(const float4*)(b_dw + c4);
    ushort4 av = *(const ushort4*)(attb + ((size_t)pix << 8) + c4);
    float4 acc;
    acc.x = h2f(av.x) + bv.x; acc.y = h2f(av.y) + bv.y;
    acc.z = h2f(av.z) + bv.z; acc.w = h2f(av.w) + bv.w;

#pragma unroll
    for (int ky = 0; ky < 3; ky++) {
        int yy = y + ky - 1;
        if (yy < 0 || yy > 127) continue;
#pragma unroll
        for (int kx = 0; kx < 3; kx++) {
            int xx = x + kx - 1;
            if (xx < 0 || xx > 127) continue;
            int j = ky * 3 + kx;
            ushort4 v = *(const ushort4*)(qkvb + (((size_t)bb << 14) + yy * 128 + xx) * 768 + 512 + c4);
            acc.x = fmaf(h2f(v.x), wreg[0 * 9 + j], acc.x);
            acc.y = fmaf(h2f(v.y), wreg[1 * 9 + j], acc.y);
            acc.z = fmaf(h2f(v.z), wreg[2 * 9 + j], acc.z);
            acc.w = fmaf(h2f(v.w), wreg[3 * 9 + j], acc.w);
        }
    }
    ushort4 r;
    r.x = f2h(acc.x); r.y = f2h(acc.y); r.z = f2h(acc.z); r.w = f2h(acc.w);
    *(ushort4*)(attb + ((size_t)pix << 8) + c4) = r;
}

// ---------------------------------------------------------------------------
extern "C" void kernel_launch(void* const* d_in, const int* in_sizes, int n_in,
                              void* d_out, int out_size, void* d_ws, size_t ws_size,
                              hipStream_t stream) {
    const float* x     = (const float*)d_in[0];
    const float* w_qkv = (const float*)d_in[1];
    const float* w_proj= (const float*)d_in[2];
    const float* b_proj= (const float*)d_in[3];
    const float* w_dw  = (const float*)d_in[4];
    const float* b_dw  = (const float*)d_in[5];
    const float* pp_w  = (const float*)d_in[6];
    const float* pp_b  = (const float*)d_in[7];
    const float* ln1_g = (const float*)d_in[8];
    const float* ln1_b = (const float*)d_in[9];
    const float* l1_w  = (const float*)d_in[10];
    const float* l1_b  = (const float*)d_in[11];
    const float* ln2_g = (const float*)d_in[12];
    const float* ln2_b = (const float*)d_in[13];
    const float* l2_w  = (const float*)d_in[14];
    const float* l2_b  = (const float*)d_in[15];
    const float* ln3_g = (const float*)d_in[16];
    const float* ln3_b = (const float*)d_in[17];
    const float* l3_w  = (const float*)d_in[18];
    const float* l3_b  = (const float*)d_in[19];

    // Workspace layout (~162.5 MiB):
    float* pos = (float*)d_ws;                               // 7,680 f
    float* T2  = pos + 7680;                                 // 524,288 f
    unsigned short* qkvb = (unsigned short*)(T2 + 524288);   // 65536*768 sh (96 MiB, fp16)
    unsigned short* attb = qkvb + (size_t)NROWS * 768;       // 65536*256 sh (32 MiB, fp16)
    unsigned short* xh   = attb + (size_t)NROWS * 256;       // 32 MiB fp16
    unsigned short* wqh  = xh + (size_t)NROWS * 256;         // 196,608 sh
    unsigned short* wph  = wqh + 768 * 256;                  // 65,536 sh

    pos_kernel<<<2, 128, 0, stream>>>(pp_w, pp_b, ln1_g, ln1_b, l1_w, l1_b,
                                      ln2_g, ln2_b, l2_w, l2_b, ln3_g, ln3_b,
                                      l3_w, l3_b, pos);
    rpb_kernel<<<dim3(256, 4, 2), 256, 0, stream>>>(pos, T2);
    convw_kernel<<<768, 256, 0, stream>>>(w_qkv, wqh, 256, 768);
    convw_kernel<<<256, 256, 0, stream>>>(w_proj, wph, 256, 256);
    convx_kernel<<<NROWS / 4, 256, 0, stream>>>(x, xh);
    // qkv_f16 = x @ w_qkv   (single-term fp16, global_load_lds staging, XCD swizzle)
    gemm_f16<<<(NROWS / 128) * 6, 256, 0, stream>>>(xh, wqh, qkvb, 768, 6);
    // window attention -> attb (fp16)
    attn_mfma<<<dim3(256, 4, 2), 256, 0, stream>>>(qkvb, T2, attb);
    // LePE += depthwise conv on V (fp16 RMW)
    lepe_kernel<<<(B_ * LL) / 4, 256, 0, stream>>>(qkvb, w_dw, b_dw, attb);
    // d_out = attb @ w_proj + b_proj  (single-term fp16, fp32 out, direct to d_out)
    gemm_proj<<<(NROWS / 128) * 2, 256, 0, stream>>>(attb, wph, (float*)d_out, b_proj);
}